// Round 1
// baseline (369.918 us; speedup 1.0000x reference)
//
#include <hip/hip_runtime.h>
#include <math.h>

#define NB 8192
#define BATCH 2
#define KNN 20
#define BN (BATCH*NB)
#define NE (BN*KNN)   // 327680 edges total

__device__ __forceinline__ float gelu_f(float x){
    // jax.nn.gelu default (approximate=True, tanh form)
    float x3 = x*x*x;
    float a = 0.7978845608028654f*(x + 0.044715f*x3);
    float e2 = __expf(2.0f*a);
    float th = 1.0f - 2.0f/(e2+1.0f);   // tanh(a), safe at +/-inf
    return 0.5f*x*(1.0f+th);
}

// ---------------- K0: prep pos4 {x,y,z,r2} and vel4 {vx,vy,vz,massf} ----------------
__global__ __launch_bounds__(256) void prep_kernel(const float* __restrict__ z,
                                                   float4* __restrict__ pos4,
                                                   float4* __restrict__ vel4){
    int g = blockIdx.x*256 + threadIdx.x;
    if (g >= BN) return;
    const float* zp = z + (size_t)g*7;
    float x = zp[0], y = zp[1], zz = zp[2];
    float r2 = x*x + y*y + zz*zz;
    pos4[g] = make_float4(x, y, zz, r2);
    vel4[g] = make_float4(zp[3], zp[4], zp[5], zp[6]);
}

// ---------------- K1: cond MLP + collapsed constants ----------------
// consts layout (floats): C[2][128] @0, S1[128] @256, S2[128] @384, D[2][64] @512, T1[64] @640
__global__ __launch_bounds__(256) void cond_kernel(const float* __restrict__ t,
        const float* __restrict__ conditioning,
        const float* __restrict__ Wc1, const float* __restrict__ bc1,
        const float* __restrict__ Wc2, const float* __restrict__ bc2,
        const float* __restrict__ Wc3, const float* __restrict__ bc3,
        const float* __restrict__ We1, const float* __restrict__ be1,
        const float* __restrict__ Wn1, const float* __restrict__ bn1,
        float* __restrict__ consts){
    int b = blockIdx.x;
    int tid = threadIdx.x;
    __shared__ float ci[36];
    __shared__ float h1[144];
    __shared__ float h2[144];
    __shared__ float cnd[36];
    float tv = t[b];
    if (tid < 16){
        float f = expf(-9.210340371976184f * (float)tid / 15.0f);
        float a = tv*f;
        ci[tid]    = sinf(a);
        ci[16+tid] = cosf(a);
    }
    if (tid < 4) ci[32+tid] = conditioning[b*4+tid];
    __syncthreads();
    if (tid < 144){
        float acc = bc1[tid];
        for (int c=0;c<36;c++) acc += ci[c]*Wc1[c*144+tid];
        h1[tid] = gelu_f(acc);
    }
    __syncthreads();
    if (tid < 144){
        float acc = bc2[tid];
        for (int c=0;c<144;c++) acc += h1[c]*Wc2[c*144+tid];
        h2[tid] = gelu_f(acc);
    }
    __syncthreads();
    if (tid < 36){
        float acc = bc3[tid];
        for (int c=0;c<144;c++) acc += h2[c]*Wc3[c*36+tid];
        cnd[tid] = acc;
    }
    __syncthreads();
    if (tid < 128){
        float accC = be1[tid], s1 = 0.f, s2 = 0.f;
        for (int c=0;c<36;c++){
            float w1 = We1[c*128+tid];
            float w2 = We1[(36+c)*128+tid];
            accC += cnd[c]*(w1+w2);
            s1 += w1; s2 += w2;
        }
        consts[b*128+tid] = accC;
        if (b==0){ consts[256+tid] = s1; consts[384+tid] = s2; }
    }
    if (tid < 64){
        float accD = bn1[tid], t1 = 0.f;
        for (int c=0;c<36;c++){
            float w = Wn1[c*64+tid];
            accD += cnd[c]*w;
            t1 += w;
        }
        consts[512 + b*64 + tid] = accD;
        if (b==0) consts[640+tid] = t1;
    }
}

// ---------------- K2: brute-force exact KNN, wave per node ----------------
__global__ __launch_bounds__(256) void knn_kernel(const float4* __restrict__ pos4,
                                                  int* __restrict__ nbr){
    int wave = threadIdx.x >> 6;
    int lane = threadIdx.x & 63;
    int g = blockIdx.x*4 + wave;       // global node id
    int b = g >> 13;
    int i = g & (NB-1);
    const float4* P = pos4 + b*NB;
    float4 pi = P[i];

    float bd[8]; int bi[8];
    #pragma unroll
    for (int s=0;s<8;s++){ bd[s] = 3.0e38f; bi[s] = 0x7fffffff; }

    for (int tk=0; tk<NB/64; ++tk){
        int j = lane + (tk<<6);
        float4 q = P[j];
        float dot = pi.x*q.x + pi.y*q.y + pi.z*q.z;
        float d2 = (pi.w + q.w) - 2.0f*dot;   // reference formula
        if (j == i) d2 = 3.0e38f;             // self excluded (1e10*eye)
        if (d2 < bd[7]){
            float vd = d2; int vi = j;
            #pragma unroll
            for (int s=0;s<8;s++){
                bool c = vd < bd[s];
                float td = bd[s]; int ti = bi[s];
                bd[s] = c ? vd : td;  bi[s] = c ? vi : ti;
                vd    = c ? td : vd;  vi    = c ? ti : vi;
            }
        }
    }

    // merge 64 sorted 8-lists -> global top-20, index tiebreak (matches top_k)
    int* outp = nbr + (size_t)g*KNN;
    for (int r=0; r<KNN; r++){
        float d = bd[0]; int ii = bi[0];
        #pragma unroll
        for (int s=1; s<64; s<<=1){
            float od = __shfl_xor(d, s);
            int   oi = __shfl_xor(ii, s);
            if (od < d || (od == d && oi < ii)){ d = od; ii = oi; }
        }
        if (lane == 0) outp[r] = ii;
        if (bd[0] == d && bi[0] == ii){   // winner pops (unique: ii unique)
            #pragma unroll
            for (int s=0;s<7;s++){ bd[s]=bd[s+1]; bi[s]=bi[s+1]; }
            bd[7] = 3.0e38f; bi[7] = 0x7fffffff;
        }
    }
}

// ---------------- K3: edge MLP (collapsed), thread per edge ----------------
// ebuf layout: logit[NE], smsg[NE], ux[NE], uy[NE], uz[NE]
__global__ __launch_bounds__(256) void edge_kernel(const float4* __restrict__ pos4,
        const float4* __restrict__ vel4,
        const int* __restrict__ nbr,
        const float* __restrict__ consts,
        const float* __restrict__ We1,
        const float* __restrict__ We2,
        const float* __restrict__ be2,
        float* __restrict__ ebuf){
    __shared__ float sC[2][128], sS1[128], sS2[128];
    __shared__ float sW72[128], sW73[128], sW74[128], sW75[128];
    __shared__ float sW2[128*4];
    int tid = threadIdx.x;
    if (tid < 128){
        sC[0][tid] = consts[tid];
        sC[1][tid] = consts[128+tid];
        sS1[tid]   = consts[256+tid];
        sS2[tid]   = consts[384+tid];
        sW72[tid]  = We1[72*128+tid];
        sW73[tid]  = We1[73*128+tid];
        sW74[tid]  = We1[74*128+tid];
        sW75[tid]  = We1[75*128+tid];
    }
    for (int k=tid; k<512; k+=256) sW2[k] = We2[k];
    __syncthreads();

    int e = blockIdx.x*256 + tid;      // < NE
    int i = e / KNN;                   // global node (tgt)
    int b = i >> 13;
    int s = nbr[e];                    // local src within batch
    float4 ps = pos4[b*NB + s];
    float4 pt = pos4[i];
    float4 vs = vel4[b*NB + s];
    float4 vt = vel4[i];
    float rx = ps.x - pt.x, ry = ps.y - pt.y, rz = ps.z - pt.z;
    float r2  = rx*rx + ry*ry + rz*rz;
    float vv  = vs.x*vt.x + vs.y*vt.y + vs.z*vt.z;
    float vsr = vs.x*rx + vs.y*ry + vs.z*rz;
    float vtr = vt.x*rx + vt.y*ry + vt.z*rz;
    float mfs = vs.w, mft = vt.w;

    float e0 = be2[0], e1 = be2[1], e2v = be2[2], e3 = be2[3];
    #pragma unroll 4
    for (int h=0; h<128; h++){
        float x = sC[b][h] + mfs*sS1[h] + mft*sS2[h]
                + r2*sW72[h] + vv*sW73[h] + vsr*sW74[h] + vtr*sW75[h];
        float gx = gelu_f(x);
        e0  += gx*sW2[h*4+0];
        e1  += gx*sW2[h*4+1];
        e2v += gx*sW2[h*4+2];
        e3  += gx*sW2[h*4+3];
    }
    ebuf[e]        = e0;                    // logit
    ebuf[NE + e]   = e1;                    // smsg
    ebuf[2*NE + e] = e2v*rx + e3*vs.x;      // u = c_rel*rel + c_vel*vs
    ebuf[3*NE + e] = e2v*ry + e3*vs.y;
    ebuf[4*NE + e] = e2v*rz + e3*vs.z;
}

// ---------------- K4: softmax + aggregate + node MLP + output, thread per node ----------------
__global__ __launch_bounds__(256) void node_kernel(const float* __restrict__ z,
        const float4* __restrict__ vel4,
        const float* __restrict__ consts,
        const float* __restrict__ Wn1,
        const float* __restrict__ Wn2,
        const float* __restrict__ bn2,
        const float* __restrict__ alpha_p,
        const float* __restrict__ beta_p,
        const float* __restrict__ ebuf,
        float* __restrict__ out){
    __shared__ float sD[2][64], sT1[64], sW36[64], sWo[64];
    int tid = threadIdx.x;
    if (tid < 64){
        sD[0][tid] = consts[512+tid];
        sD[1][tid] = consts[576+tid];
        sT1[tid]   = consts[640+tid];
        sW36[tid]  = Wn1[36*64+tid];
        sWo[tid]   = Wn2[tid];
    }
    __syncthreads();

    int g = blockIdx.x*256 + tid;      // < BN
    int b = g >> 13;

    float lg[KNN];
    float m = -3.0e38f;
    #pragma unroll
    for (int r=0;r<KNN;r++){ lg[r] = ebuf[g*KNN + r]; m = fmaxf(m, lg[r]); }
    float denom = 0.f;
    #pragma unroll
    for (int r=0;r<KNN;r++){ lg[r] = expf(lg[r]-m); denom += lg[r]; }
    float inv = 1.0f/denom;
    float vax=0.f, vay=0.f, vaz=0.f, sagg=0.f;
    #pragma unroll
    for (int r=0;r<KNN;r++){
        float w = lg[r]*inv;
        int e = g*KNN + r;
        sagg += w*ebuf[NE + e];
        vax  += w*ebuf[2*NE + e];
        vay  += w*ebuf[3*NE + e];
        vaz  += w*ebuf[4*NE + e];
    }

    float mf = vel4[g].w;
    float sout = bn2[0];
    #pragma unroll 4
    for (int h=0; h<64; h++){
        float x = sD[b][h] + mf*sT1[h] + sagg*sW36[h];
        sout += gelu_f(x)*sWo[h];
    }

    float alpha = alpha_p[0], beta = beta_p[0];
    const float* zp = z + (size_t)g*7;
    float* op = out + (size_t)g*7;
    op[0] = zp[0] + zp[0] + alpha*vax;   // z + (pos + a*vagg), pos==z[:3]
    op[1] = zp[1] + zp[1] + alpha*vay;
    op[2] = zp[2] + zp[2] + alpha*vaz;
    op[3] = zp[3] + beta*vax;
    op[4] = zp[4] + beta*vay;
    op[5] = zp[5] + beta*vaz;
    op[6] = zp[6] + sout;
}

extern "C" void kernel_launch(void* const* d_in, const int* in_sizes, int n_in,
                              void* d_out, int out_size, void* d_ws, size_t ws_size,
                              hipStream_t stream) {
    const float* z    = (const float*)d_in[0];
    const float* t    = (const float*)d_in[1];
    const float* cond = (const float*)d_in[2];
    // d_in[3] = mask (unused by reference)
    const float* Wc1  = (const float*)d_in[4];
    const float* bc1  = (const float*)d_in[5];
    const float* Wc2  = (const float*)d_in[6];
    const float* bc2  = (const float*)d_in[7];
    const float* Wc3  = (const float*)d_in[8];
    const float* bc3  = (const float*)d_in[9];
    const float* We1  = (const float*)d_in[10];
    const float* be1  = (const float*)d_in[11];
    const float* We2  = (const float*)d_in[12];
    const float* be2  = (const float*)d_in[13];
    const float* Wn1  = (const float*)d_in[14];
    const float* bn1  = (const float*)d_in[15];
    const float* Wn2  = (const float*)d_in[16];
    const float* bn2  = (const float*)d_in[17];
    const float* alp  = (const float*)d_in[18];
    const float* bet  = (const float*)d_in[19];
    float* out = (float*)d_out;

    char* ws = (char*)d_ws;
    float4* pos4  = (float4*)(ws);                       // BN*16 = 262144 B
    float4* vel4  = (float4*)(ws + 262144);              // 262144 B
    float*  consts= (float*)(ws + 524288);               // 704 floats
    int*    nbr   = (int*)(ws + 524288 + 4096);          // NE*4 = 1310720 B
    float*  ebuf  = (float*)(ws + 524288 + 4096 + 1310720); // 5*NE*4 = 6553600 B

    prep_kernel<<<dim3(BN/256), dim3(256), 0, stream>>>(z, pos4, vel4);
    cond_kernel<<<dim3(BATCH), dim3(256), 0, stream>>>(t, cond, Wc1, bc1, Wc2, bc2,
                                                       Wc3, bc3, We1, be1, Wn1, bn1, consts);
    knn_kernel<<<dim3(BN/4), dim3(256), 0, stream>>>(pos4, nbr);
    edge_kernel<<<dim3(NE/256), dim3(256), 0, stream>>>(pos4, vel4, nbr, consts, We1, We2, be2, ebuf);
    node_kernel<<<dim3(BN/256), dim3(256), 0, stream>>>(z, vel4, consts, Wn1, Wn2, bn2,
                                                        alp, bet, ebuf, out);
}